// Round 5
// baseline (233.208 us; speedup 1.0000x reference)
//
#include <hip/hip_runtime.h>
#include <hip/hip_bf16.h>
#include <stdint.h>

#define B_  2
#define S_  2048
#define H_  512
#define NH_ 8
#define DK_ 64

typedef __bf16 bf16x8 __attribute__((ext_vector_type(8)));
typedef short  s16x4  __attribute__((ext_vector_type(4)));
typedef float  f32x4  __attribute__((ext_vector_type(4)));

static __device__ __forceinline__ uint32_t pk2(float a, float b) {
  __hip_bfloat162 h = __float22bfloat162_rn(float2{a, b});
  uint32_t u;
  __builtin_memcpy(&u, &h, 4);
  return u;
}
static __device__ __forceinline__ uint4 pkf8(float4 a, float4 b) {
  return uint4{pk2(a.x, a.y), pk2(a.z, a.w), pk2(b.x, b.y), pk2(b.z, b.w)};
}

// 16x16x16 bf16 MFMA. Guard with __HIP_DEVICE_COMPILE__ (host pass lacks
// device builtins — R3 compile failure).
static __device__ __forceinline__ f32x4 mfma_k16(s16x4 a, s16x4 b, f32x4 c) {
#if defined(__HIP_DEVICE_COMPILE__)
  return __builtin_amdgcn_mfma_f32_16x16x16bf16_1k(a, b, c, 0, 0, 0);
#else
  (void)a; (void)b;
  return c;
#endif
}

typedef const __attribute__((address_space(1))) uint32_t* gas_t;
typedef __attribute__((address_space(3))) uint32_t* las_t;
static __device__ __forceinline__ void cp16(const void* g, void* l) {
  __builtin_amdgcn_global_load_lds((gas_t)g, (las_t)l, 16, 0, 0);
}

// ---------------------------------------------------------------------------
// Kernel 1 (fused): proj (blocks 0..767) + bias zero-scan (768..4863) + fmL
// (4864). No atomics, no memset: scan emits per-(b,q)-row 32-bit masks,
// bit c = "some bias==0 in k-chunk [c*64,(c+1)*64)".
// ---------------------------------------------------------------------------
struct ProjArgs {
  const float* X[3];
  const float* W[3];
  const float* Bv[3];
  uint16_t*    O[3];
  const float* bias;
  const int*   mask;
  uint32_t*    zrow;
  float*       fmL;
};

__global__ __launch_bounds__(256) void prep_proj_kernel(ProjArgs pa) {
  __shared__ __align__(16) char psm[24640];
  int bid = blockIdx.x, t = threadIdx.x;

  if (bid >= 768) {
    if (bid < 4864) {
      // ---- bias zero-scan: one (b,q) row (2048 k) per block ----
      int r = bid - 768;
      uint32_t* wbuf = (uint32_t*)psm;
      const uint4* src = (const uint4*)(pa.bias + (size_t)r * 2048 + t * 8);
      uint4 a = src[0], b2 = src[1];
      bool z = ((a.x << 1) == 0u) | ((a.y << 1) == 0u) |
               ((a.z << 1) == 0u) | ((a.w << 1) == 0u) |
               ((b2.x << 1) == 0u) | ((b2.y << 1) == 0u) |
               ((b2.z << 1) == 0u) | ((b2.w << 1) == 0u);
      uint64_t m = __ballot(z);
      if ((t & 63) == 0) {
        uint32_t bits = 0;
#pragma unroll
        for (int c = 0; c < 8; c++)
          bits |= (uint32_t)(((m >> (8 * c)) & 0xFFull) != 0ull) << c;
        wbuf[t >> 6] = bits;
      }
      __syncthreads();
      if (t == 0)
        pa.zrow[r] = wbuf[0] | (wbuf[1] << 8) | (wbuf[2] << 16) | (wbuf[3] << 24);
    } else {
      // ---- fmL = mask * log2(e) ----
      const float LOG2E = 1.44269504088896340736f;
#pragma unroll
      for (int i = 0; i < 16; i++) {
        int idx = i * 256 + t;
        pa.fmL[idx] = (float)pa.mask[idx] * LOG2E;
      }
    }
    return;
  }

  // ---- proj: y = x @ W^T + b, tile 128 s x 64 d ----
  int mat = bid / 256;
  int rem = bid & 255;
  int mtile = rem >> 3, dtile = rem & 7;
  int m0 = mtile * 128, n0 = dtile * 64;
  const float* X  = pa.X[mat];
  const float* Wt = pa.W[mat];
  const float* Bv = pa.Bv[mat];
  uint16_t*    O  = pa.O[mat];

  uint16_t (*Xs)[64] = (uint16_t (*)[64])psm;             // [128][64] 16 KB
  uint16_t (*Ws)[64] = (uint16_t (*)[64])(psm + 16384);   // [64][64]   8 KB

  int w = t >> 6, l = t & 63, lo = l & 15, g = l >> 4;
  int srow = t >> 1, shalf = t & 1;
  int wrow = t >> 2, wq = t & 3;

  const float* Xrow = X + (size_t)(m0 + srow) * 512 + shalf * 32;
  const float* Wrow = Wt + (size_t)(n0 + wrow) * 512 + wq * 16;

  f32x4 acc[2][4];
#pragma unroll
  for (int st = 0; st < 2; st++)
#pragma unroll
    for (int dt = 0; dt < 4; dt++) acc[st][dt] = (f32x4){0.f, 0.f, 0.f, 0.f};

  float4 xa[8], wa2[4];
  {
    const float4* sx = (const float4*)Xrow;
    const float4* sw = (const float4*)Wrow;
#pragma unroll
    for (int i = 0; i < 8; i++) xa[i] = sx[i];
#pragma unroll
    for (int i = 0; i < 4; i++) wa2[i] = sw[i];
  }

  for (int kb = 0; kb < 8; kb++) {
#pragma unroll
    for (int j = 0; j < 4; j++) {
      int s = (shalf * 4 + j) ^ (srow & 7);
      *(uint4*)&Xs[srow][s * 8] = pkf8(xa[2 * j], xa[2 * j + 1]);
    }
#pragma unroll
    for (int j = 0; j < 2; j++) {
      int s = (wq * 2 + j) ^ (wrow & 7);
      *(uint4*)&Ws[wrow][s * 8] = pkf8(wa2[2 * j], wa2[2 * j + 1]);
    }
    __syncthreads();
    if (kb < 7) {
      const float4* sx = (const float4*)(Xrow + (kb + 1) * 64);
      const float4* sw = (const float4*)(Wrow + (kb + 1) * 64);
#pragma unroll
      for (int i = 0; i < 8; i++) xa[i] = sx[i];
#pragma unroll
      for (int i = 0; i < 4; i++) wa2[i] = sw[i];
    }
#pragma unroll
    for (int kk = 0; kk < 2; kk++) {
      int seg = (kk * 4 + g) ^ (lo & 7);
      bf16x8 xf[2], wf[4];
#pragma unroll
      for (int st = 0; st < 2; st++)
        xf[st] = *(const bf16x8*)&Xs[w * 32 + st * 16 + lo][seg * 8];
#pragma unroll
      for (int dt = 0; dt < 4; dt++)
        wf[dt] = *(const bf16x8*)&Ws[dt * 16 + lo][seg * 8];
      if (mat < 2) {
#pragma unroll
        for (int st = 0; st < 2; st++)
#pragma unroll
          for (int dt = 0; dt < 4; dt++)
            acc[st][dt] = __builtin_amdgcn_mfma_f32_16x16x32_bf16(wf[dt], xf[st], acc[st][dt], 0, 0, 0);
      } else {
#pragma unroll
        for (int st = 0; st < 2; st++)
#pragma unroll
          for (int dt = 0; dt < 4; dt++)
            acc[st][dt] = __builtin_amdgcn_mfma_f32_16x16x32_bf16(xf[st], wf[dt], acc[st][dt], 0, 0, 0);
      }
    }
    __syncthreads();
  }

  if (mat < 2) {
    float scale = (mat == 0) ? 0.125f : 1.0f;
    float4 bv4[4];
#pragma unroll
    for (int dt = 0; dt < 4; dt++)
      bv4[dt] = *(const float4*)(Bv + n0 + dt * 16 + g * 4);
#pragma unroll
    for (int st = 0; st < 2; st++) {
      int ss = m0 + w * 32 + st * 16 + lo;
      int bb = ss >> 11, sIn = ss & 2047;
      uint16_t* obase = O + ((size_t)(bb * NH_ + dtile) * S_ + sIn) * DK_;
#pragma unroll
      for (int dt = 0; dt < 4; dt++) {
        float v0 = (acc[st][dt][0] + bv4[dt].x) * scale;
        float v1 = (acc[st][dt][1] + bv4[dt].y) * scale;
        float v2 = (acc[st][dt][2] + bv4[dt].z) * scale;
        float v3 = (acc[st][dt][3] + bv4[dt].w) * scale;
        uint2 pk{pk2(v0, v1), pk2(v2, v3)};
        *(uint2*)(obase + dt * 16 + g * 4) = pk;
      }
    }
  } else {
    float bval[4];
#pragma unroll
    for (int dt = 0; dt < 4; dt++) bval[dt] = Bv[n0 + dt * 16 + lo];
#pragma unroll
    for (int st = 0; st < 2; st++) {
      int m = m0 + w * 32 + st * 16 + g * 4;
      int bb = m >> 11, sIn = m & 2047;
#pragma unroll
      for (int dt = 0; dt < 4; dt++) {
        int dd = dt * 16 + lo;
        float v0 = acc[st][dt][0] + bval[dt];
        float v1 = acc[st][dt][1] + bval[dt];
        float v2 = acc[st][dt][2] + bval[dt];
        float v3 = acc[st][dt][3] + bval[dt];
        uint2 pk{pk2(v0, v1), pk2(v2, v3)};
        *(uint2*)(O + ((size_t)(bb * NH_ + dtile) * DK_ + dd) * S_ + sIn) = pk;
      }
    }
  }
}

// ---------------------------------------------------------------------------
// Kernel 2: flash attention. 512 threads (8 waves), k-tile 128, each wave owns
// a 16-k slice; P register-resident (QK C-frag == PV A/B pairing for
// 16x16x16). 2 blocks/CU -> 16 waves/CU. No-max softmax (scores bounded).
// ---------------------------------------------------------------------------
__global__ __launch_bounds__(512, 4) void attn_kernel(
    const uint16_t* __restrict__ Qb, const uint16_t* __restrict__ Kb,
    const uint16_t* __restrict__ Vt, const uint32_t* __restrict__ zrow,
    const float* __restrict__ fmL, const float* __restrict__ bias,
    float* __restrict__ out) {
  int bid = blockIdx.x;
  int bh = bid & 15, qtile = bid >> 4;   // bid%8 spreads heads across XCDs
  int b = bh >> 3, h = bh & 7;
  int q0 = qtile * 64;
  int t = threadIdx.x;
  int w = t >> 6, l = t & 63, lo = l & 15, g = l >> 4;

  __shared__ __align__(16) char smem[65536];
  uint16_t* KsB = (uint16_t*)smem;              // [2][128 k][64 d]  32 KB
  uint16_t* VsB = (uint16_t*)(smem + 32768);    // [2][64 d][128 k]  32 KB

  const uint16_t* Qh = Qb + (size_t)bh * S_ * DK_;
  const uint16_t* Kh = Kb + (size_t)bh * S_ * DK_;
  const uint16_t* Vh = Vt + (size_t)bh * DK_ * S_;

  // K staging: wave w covers k-rows [w*16, w*16+16); LDS(row,s)=glob(row,s^(row&7))
  int lrow = l >> 3, lseg = (l & 7) ^ lrow;
  const uint16_t* kbase = Kh + (size_t)(w * 16 + lrow) * DK_ + lseg * 8;
  uint16_t* kd0 = KsB + (w * 16) * 64;
  uint16_t* kd8 = KsB + (w * 16 + 8) * 64;
  // V staging: call c covers d-rows [c*32 + w*4, +4); 16 segs of 8 elems,
  // LDS(d,s) = glob(d, s ^ (d&15)).
  int vrow0 = w * 4 + (l >> 4);
  int vrow1 = 32 + w * 4 + (l >> 4);
  const uint16_t* vb0 = Vh + (size_t)vrow0 * S_ + (((l & 15) ^ (vrow0 & 15)) * 8);
  const uint16_t* vb1 = Vh + (size_t)vrow1 * S_ + (((l & 15) ^ (vrow1 & 15)) * 8);
  uint16_t* vd0 = VsB + (w * 4) * 128;
  uint16_t* vd1 = VsB + (32 + w * 4) * 128;

  // block-uniform zero-bias mask: bit c => some bias==0 in k-chunk c (64k)
  uint32_t zall = zrow[(b << 11) + q0 + l];
#pragma unroll
  for (int s = 1; s < 64; s <<= 1) zall |= __shfl_xor(zall, s);

  // Register-resident Q fragments (B-operand of QK), 4 q-subtiles x K=64.
  bf16x8 qf[4][2];
#pragma unroll
  for (int qt = 0; qt < 4; qt++)
#pragma unroll
    for (int kk = 0; kk < 2; kk++)
      qf[qt][kk] = *(const bf16x8*)(Qh + (size_t)(q0 + qt * 16 + lo) * DK_ + kk * 32 + g * 8);

  f32x4 o[4][4];
#pragma unroll
  for (int dt = 0; dt < 4; dt++)
#pragma unroll
    for (int qt = 0; qt < 4; qt++) o[dt][qt] = (f32x4){0.f, 0.f, 0.f, 0.f};
  float ts[4] = {0.f, 0.f, 0.f, 0.f};

  const float* fmrow = fmL + b * S_ + w * 16 + g * 4;
  const float LOG2E = 1.44269504088896340736f;

  // stage tile 0
  cp16(kbase, kd0);
  cp16(kbase + 8 * DK_, kd8);
  cp16(vb0, vd0);
  cp16(vb1, vd1);

  for (int kb = 0; kb < 16; kb++) {
    int cur = kb & 1;
    int k0 = kb * 128;
    float4 mv4 = *(const float4*)(fmrow + k0);
    __syncthreads();                             // drains DMA for tile kb
    if (kb + 1 < 16) {
      int kn = k0 + 128;
      int nb = (cur ^ 1) * 8192;
      cp16(kbase + (size_t)kn * DK_, kd0 + nb);
      cp16(kbase + (size_t)kn * DK_ + 8 * DK_, kd8 + nb);
      cp16(vb0 + kn, vd0 + nb);
      cp16(vb1 + kn, vd1 + nb);
    }
    const uint16_t* KsT = KsB + cur * 8192;
    const uint16_t* VsT = VsB + cur * 8192;

    // V^T A-frags: lane (lo,g) needs V[d=dt*16+lo][k = w*16 + g*4 ..+4)
    s16x4 vf[4];
    {
      int sl = 2 * w + (g >> 1);
#pragma unroll
      for (int dt = 0; dt < 4; dt++) {
        int sp = sl ^ lo;                        // d&15 == lo
        vf[dt] = *(const s16x4*)(VsT + (dt * 16 + lo) * 128 + sp * 8 + (g & 1) * 4);
      }
    }
    // K A-frags (this wave's 16 k-rows)
    bf16x8 kf[2];
#pragma unroll
    for (int kk = 0; kk < 2; kk++) {
      int sp = (kk * 4 + g) ^ (lo & 7);
      kf[kk] = *(const bf16x8*)(KsT + (w * 16 + lo) * 64 + sp * 8);
    }

    // S^T = K * Q^T : lane holds S[k = w*16+g*4+r][q = qt*16+lo]
    f32x4 c[4];
#pragma unroll
    for (int qt = 0; qt < 4; qt++) {
      f32x4 z = {0.f, 0.f, 0.f, 0.f};
      z = __builtin_amdgcn_mfma_f32_16x16x32_bf16(kf[0], qf[qt][0], z, 0, 0, 0);
      c[qt] = __builtin_amdgcn_mfma_f32_16x16x32_bf16(kf[1], qf[qt][1], z, 0, 0, 0);
    }

    float p[4][4];
    if (((zall >> (2 * kb)) & 3u) == 0u) {   // no zero bias in these 128 k
#pragma unroll
      for (int qt = 0; qt < 4; qt++) {
        p[qt][0] = __builtin_amdgcn_exp2f(__builtin_fmaf(c[qt][0], LOG2E, mv4.x));
        p[qt][1] = __builtin_amdgcn_exp2f(__builtin_fmaf(c[qt][1], LOG2E, mv4.y));
        p[qt][2] = __builtin_amdgcn_exp2f(__builtin_fmaf(c[qt][2], LOG2E, mv4.z));
        p[qt][3] = __builtin_amdgcn_exp2f(__builtin_fmaf(c[qt][3], LOG2E, mv4.w));
      }
    } else {                                 // rare: bias==0 -> weight 0
#pragma unroll
      for (int qt = 0; qt < 4; qt++) {
        float4 bz = *(const float4*)(bias + ((size_t)(b * S_ + q0 + qt * 16 + lo)) * S_ + k0 + w * 16 + g * 4);
        p[qt][0] = (bz.x == 0.f) ? 0.f : __builtin_amdgcn_exp2f(__builtin_fmaf(c[qt][0], LOG2E, mv4.x));
        p[qt][1] = (bz.y == 0.f) ? 0.f : __builtin_amdgcn_exp2f(__builtin_fmaf(c[qt][1], LOG2E, mv4.y));
        p[qt][2] = (bz.z == 0.f) ? 0.f : __builtin_amdgcn_exp2f(__builtin_fmaf(c[qt][2], LOG2E, mv4.z));
        p[qt][3] = (bz.w == 0.f) ? 0.f : __builtin_amdgcn_exp2f(__builtin_fmaf(c[qt][3], LOG2E, mv4.w));
      }
    }

    s16x4 pf[4];
#pragma unroll
    for (int qt = 0; qt < 4; qt++) {
      ts[qt] += (p[qt][0] + p[qt][1]) + (p[qt][2] + p[qt][3]);
      union { s16x4 v; uint32_t u[2]; } uu;
      uu.u[0] = pk2(p[qt][0], p[qt][1]);
      uu.u[1] = pk2(p[qt][2], p[qt][3]);
      pf[qt] = uu.v;
    }

#pragma unroll
    for (int dt = 0; dt < 4; dt++)
#pragma unroll
      for (int qt = 0; qt < 4; qt++)
        o[dt][qt] = mfma_k16(vf[dt], pf[qt], o[dt][qt]);
  }

  // ---- epilogue: reduce 8 wave-partials (two parallel halves), store ----
  float* OTA = (float*)smem;                 // [64 d][69]  17664 B
  float* OTB = (float*)(smem + 17664);       // [64 d][69]
  float* LS  = (float*)(smem + 35328);       // [8 w][4 qt][16 lo]
#pragma unroll
  for (int qt = 0; qt < 4; qt++) {
    float v = ts[qt];
    v += __shfl_xor(v, 16);
    v += __shfl_xor(v, 32);
    ts[qt] = v;
  }
  __syncthreads();                           // main-loop LDS reads complete
  if (g == 0) {
#pragma unroll
    for (int qt = 0; qt < 4; qt++) LS[(w * 4 + qt) * 16 + lo] = ts[qt];
  }
  float* OT = (w < 4) ? OTA : OTB;
#pragma unroll
  for (int ww = 0; ww < 4; ww++) {
    if ((w & 3) == ww) {
#pragma unroll
      for (int dt = 0; dt < 4; dt++)
#pragma unroll
        for (int qt = 0; qt < 4; qt++)
#pragma unroll
          for (int r = 0; r < 4; r++) {
            int idx = (dt * 16 + g * 4 + r) * 69 + qt * 16 + lo;
            if (ww == 0) OT[idx] = o[dt][qt][r];
            else         OT[idx] += o[dt][qt][r];
          }
    }
    __syncthreads();
  }
  {
    int q = t >> 3, dseg = (t & 7) * 8;
    int qt2 = q >> 4, lo2 = q & 15;
    float lsum = 0.f;
#pragma unroll
    for (int ww = 0; ww < 8; ww++) lsum += LS[(ww * 4 + qt2) * 16 + lo2];
    float linv = 1.0f / fmaxf(lsum, 1e-30f);
    float* ob = out + ((size_t)(b * S_ + q0 + q)) * H_ + h * DK_ + dseg;
#pragma unroll
    for (int i = 0; i < 2; i++) {
      float4 v;
      v.x = (OTA[(dseg + i * 4 + 0) * 69 + q] + OTB[(dseg + i * 4 + 0) * 69 + q]) * linv;
      v.y = (OTA[(dseg + i * 4 + 1) * 69 + q] + OTB[(dseg + i * 4 + 1) * 69 + q]) * linv;
      v.z = (OTA[(dseg + i * 4 + 2) * 69 + q] + OTB[(dseg + i * 4 + 2) * 69 + q]) * linv;
      v.w = (OTA[(dseg + i * 4 + 3) * 69 + q] + OTB[(dseg + i * 4 + 3) * 69 + q]) * linv;
      *(float4*)(ob + i * 4) = v;
    }
  }
}

// ---------------------------------------------------------------------------
extern "C" void kernel_launch(void* const* d_in, const int* in_sizes, int n_in,
                              void* d_out, int out_size, void* d_ws, size_t ws_size,
                              hipStream_t stream) {
  const float* query = (const float*)d_in[0];
  const float* key   = (const float*)d_in[1];
  const float* value = (const float*)d_in[2];
  const float* bias  = (const float*)d_in[3];
  const int*   mask  = (const int*)d_in[4];
  const float* Wq = (const float*)d_in[5];
  const float* bq = (const float*)d_in[6];
  const float* Wk = (const float*)d_in[7];
  const float* bk = (const float*)d_in[8];
  const float* Wv = (const float*)d_in[9];
  const float* bv = (const float*)d_in[10];

  char* ws = (char*)d_ws;
  uint32_t* zrow = (uint32_t*)ws;                             // 16 KB
  float*    fmL  = (float*)(ws + 16384);                      // 16 KB
  uint16_t* Qb = (uint16_t*)(ws + (size_t)(1 << 20));         // 4 MB
  uint16_t* Kb = (uint16_t*)(ws + (size_t)(5 << 20));         // 4 MB
  uint16_t* Vt = (uint16_t*)(ws + (size_t)(9 << 20));         // 4 MB

  ProjArgs pa;
  pa.X[0] = query; pa.X[1] = key; pa.X[2] = value;
  pa.W[0] = Wq;    pa.W[1] = Wk;  pa.W[2] = Wv;
  pa.Bv[0] = bq;   pa.Bv[1] = bk; pa.Bv[2] = bv;
  pa.O[0] = Qb;    pa.O[1] = Kb;  pa.O[2] = Vt;
  pa.bias = bias;  pa.mask = mask;
  pa.zrow = zrow;  pa.fmL = fmL;

  prep_proj_kernel<<<4865, 256, 0, stream>>>(pa);

  attn_kernel<<<512, 512, 0, stream>>>(Qb, Kb, Vt, zrow, fmL, bias, (float*)d_out);
}

// Round 6
// 173.370 us; speedup vs baseline: 1.3451x; 1.3451x over previous
//
#include <hip/hip_runtime.h>
#include <hip/hip_bf16.h>
#include <stdint.h>

#define B_  2
#define S_  2048
#define H_  512
#define NH_ 8
#define DK_ 64

typedef __bf16 bf16x8 __attribute__((ext_vector_type(8)));
typedef short  s16x4  __attribute__((ext_vector_type(4)));
typedef float  f32x4  __attribute__((ext_vector_type(4)));

static __device__ __forceinline__ uint32_t pk2(float a, float b) {
  __hip_bfloat162 h = __float22bfloat162_rn(float2{a, b});
  uint32_t u;
  __builtin_memcpy(&u, &h, 4);
  return u;
}
static __device__ __forceinline__ uint4 pkf8(float4 a, float4 b) {
  return uint4{pk2(a.x, a.y), pk2(a.z, a.w), pk2(b.x, b.y), pk2(b.z, b.w)};
}

// 16x16x16 bf16 MFMA. Guard with __HIP_DEVICE_COMPILE__ (host pass lacks
// device builtins — R3 compile failure).
static __device__ __forceinline__ f32x4 mfma_k16(s16x4 a, s16x4 b, f32x4 c) {
#if defined(__HIP_DEVICE_COMPILE__)
  return __builtin_amdgcn_mfma_f32_16x16x16bf16_1k(a, b, c, 0, 0, 0);
#else
  (void)a; (void)b;
  return c;
#endif
}

typedef const __attribute__((address_space(1))) uint32_t* gas_t;
typedef __attribute__((address_space(3))) uint32_t* las_t;
static __device__ __forceinline__ void cp16(const void* g, void* l) {
  __builtin_amdgcn_global_load_lds((gas_t)g, (las_t)l, 16, 0, 0);
}

// ---------------------------------------------------------------------------
// Kernel 1 (fused): proj (blocks 0..767) + bias zero-scan (768..4863) + fmL
// (4864). No atomics, no memset: scan emits per-(b,q)-row 32-bit masks,
// bit c = "some bias==0 in k-chunk [c*64,(c+1)*64)".
// ---------------------------------------------------------------------------
struct ProjArgs {
  const float* X[3];
  const float* W[3];
  const float* Bv[3];
  uint16_t*    O[3];
  const float* bias;
  const int*   mask;
  uint32_t*    zrow;
  float*       fmL;
};

__global__ __launch_bounds__(256) void prep_proj_kernel(ProjArgs pa) {
  __shared__ __align__(16) char psm[24640];
  int bid = blockIdx.x, t = threadIdx.x;

  if (bid >= 768) {
    if (bid < 4864) {
      // ---- bias zero-scan: one (b,q) row (2048 k) per block ----
      int r = bid - 768;
      uint32_t* wbuf = (uint32_t*)psm;
      const uint4* src = (const uint4*)(pa.bias + (size_t)r * 2048 + t * 8);
      uint4 a = src[0], b2 = src[1];
      bool z = ((a.x << 1) == 0u) | ((a.y << 1) == 0u) |
               ((a.z << 1) == 0u) | ((a.w << 1) == 0u) |
               ((b2.x << 1) == 0u) | ((b2.y << 1) == 0u) |
               ((b2.z << 1) == 0u) | ((b2.w << 1) == 0u);
      uint64_t m = __ballot(z);
      if ((t & 63) == 0) {
        uint32_t bits = 0;
#pragma unroll
        for (int c = 0; c < 8; c++)
          bits |= (uint32_t)(((m >> (8 * c)) & 0xFFull) != 0ull) << c;
        wbuf[t >> 6] = bits;
      }
      __syncthreads();
      if (t == 0)
        pa.zrow[r] = wbuf[0] | (wbuf[1] << 8) | (wbuf[2] << 16) | (wbuf[3] << 24);
    } else {
      // ---- fmL = mask * log2(e) ----
      const float LOG2E = 1.44269504088896340736f;
#pragma unroll
      for (int i = 0; i < 16; i++) {
        int idx = i * 256 + t;
        pa.fmL[idx] = (float)pa.mask[idx] * LOG2E;
      }
    }
    return;
  }

  // ---- proj: y = x @ W^T + b, tile 128 s x 64 d ----
  int mat = bid / 256;
  int rem = bid & 255;
  int mtile = rem >> 3, dtile = rem & 7;
  int m0 = mtile * 128, n0 = dtile * 64;
  const float* X  = pa.X[mat];
  const float* Wt = pa.W[mat];
  const float* Bv = pa.Bv[mat];
  uint16_t*    O  = pa.O[mat];

  uint16_t (*Xs)[64] = (uint16_t (*)[64])psm;             // [128][64] 16 KB
  uint16_t (*Ws)[64] = (uint16_t (*)[64])(psm + 16384);   // [64][64]   8 KB

  int w = t >> 6, l = t & 63, lo = l & 15, g = l >> 4;
  int srow = t >> 1, shalf = t & 1;
  int wrow = t >> 2, wq = t & 3;

  const float* Xrow = X + (size_t)(m0 + srow) * 512 + shalf * 32;
  const float* Wrow = Wt + (size_t)(n0 + wrow) * 512 + wq * 16;

  f32x4 acc[2][4];
#pragma unroll
  for (int st = 0; st < 2; st++)
#pragma unroll
    for (int dt = 0; dt < 4; dt++) acc[st][dt] = (f32x4){0.f, 0.f, 0.f, 0.f};

  float4 xa[8], wa2[4];
  {
    const float4* sx = (const float4*)Xrow;
    const float4* sw = (const float4*)Wrow;
#pragma unroll
    for (int i = 0; i < 8; i++) xa[i] = sx[i];
#pragma unroll
    for (int i = 0; i < 4; i++) wa2[i] = sw[i];
  }

  for (int kb = 0; kb < 8; kb++) {
#pragma unroll
    for (int j = 0; j < 4; j++) {
      int s = (shalf * 4 + j) ^ (srow & 7);
      *(uint4*)&Xs[srow][s * 8] = pkf8(xa[2 * j], xa[2 * j + 1]);
    }
#pragma unroll
    for (int j = 0; j < 2; j++) {
      int s = (wq * 2 + j) ^ (wrow & 7);
      *(uint4*)&Ws[wrow][s * 8] = pkf8(wa2[2 * j], wa2[2 * j + 1]);
    }
    __syncthreads();
    if (kb < 7) {
      const float4* sx = (const float4*)(Xrow + (kb + 1) * 64);
      const float4* sw = (const float4*)(Wrow + (kb + 1) * 64);
#pragma unroll
      for (int i = 0; i < 8; i++) xa[i] = sx[i];
#pragma unroll
      for (int i = 0; i < 4; i++) wa2[i] = sw[i];
    }
#pragma unroll
    for (int kk = 0; kk < 2; kk++) {
      int seg = (kk * 4 + g) ^ (lo & 7);
      bf16x8 xf[2], wf[4];
#pragma unroll
      for (int st = 0; st < 2; st++)
        xf[st] = *(const bf16x8*)&Xs[w * 32 + st * 16 + lo][seg * 8];
#pragma unroll
      for (int dt = 0; dt < 4; dt++)
        wf[dt] = *(const bf16x8*)&Ws[dt * 16 + lo][seg * 8];
      if (mat < 2) {
#pragma unroll
        for (int st = 0; st < 2; st++)
#pragma unroll
          for (int dt = 0; dt < 4; dt++)
            acc[st][dt] = __builtin_amdgcn_mfma_f32_16x16x32_bf16(wf[dt], xf[st], acc[st][dt], 0, 0, 0);
      } else {
#pragma unroll
        for (int st = 0; st < 2; st++)
#pragma unroll
          for (int dt = 0; dt < 4; dt++)
            acc[st][dt] = __builtin_amdgcn_mfma_f32_16x16x32_bf16(xf[st], wf[dt], acc[st][dt], 0, 0, 0);
      }
    }
    __syncthreads();
  }

  if (mat < 2) {
    float scale = (mat == 0) ? 0.125f : 1.0f;
    float4 bv4[4];
#pragma unroll
    for (int dt = 0; dt < 4; dt++)
      bv4[dt] = *(const float4*)(Bv + n0 + dt * 16 + g * 4);
#pragma unroll
    for (int st = 0; st < 2; st++) {
      int ss = m0 + w * 32 + st * 16 + lo;
      int bb = ss >> 11, sIn = ss & 2047;
      uint16_t* obase = O + ((size_t)(bb * NH_ + dtile) * S_ + sIn) * DK_;
#pragma unroll
      for (int dt = 0; dt < 4; dt++) {
        float v0 = (acc[st][dt][0] + bv4[dt].x) * scale;
        float v1 = (acc[st][dt][1] + bv4[dt].y) * scale;
        float v2 = (acc[st][dt][2] + bv4[dt].z) * scale;
        float v3 = (acc[st][dt][3] + bv4[dt].w) * scale;
        uint2 pk{pk2(v0, v1), pk2(v2, v3)};
        *(uint2*)(obase + dt * 16 + g * 4) = pk;
      }
    }
  } else {
    float bval[4];
#pragma unroll
    for (int dt = 0; dt < 4; dt++) bval[dt] = Bv[n0 + dt * 16 + lo];
#pragma unroll
    for (int st = 0; st < 2; st++) {
      int m = m0 + w * 32 + st * 16 + g * 4;
      int bb = m >> 11, sIn = m & 2047;
#pragma unroll
      for (int dt = 0; dt < 4; dt++) {
        int dd = dt * 16 + lo;
        float v0 = acc[st][dt][0] + bval[dt];
        float v1 = acc[st][dt][1] + bval[dt];
        float v2 = acc[st][dt][2] + bval[dt];
        float v3 = acc[st][dt][3] + bval[dt];
        uint2 pk{pk2(v0, v1), pk2(v2, v3)};
        *(uint2*)(O + ((size_t)(bb * NH_ + dtile) * DK_ + dd) * S_ + sIn) = pk;
      }
    }
  }
}

// ---------------------------------------------------------------------------
// Kernel 2: flash attention. R4 structure (verified: 256 thr, 4 waves, k-tile
// 64, no spills) with q-tile 32 -> grid 1024 -> 4 blocks/CU = 16 waves/CU.
// R5 lesson: do NOT buy occupancy with a launch-bounds VGPR cap below the
// live-register footprint (VGPR 64 forced o[][] spills -> 190 MB scratch).
// ---------------------------------------------------------------------------
__global__ __launch_bounds__(256, 2) void attn_kernel(
    const uint16_t* __restrict__ Qb, const uint16_t* __restrict__ Kb,
    const uint16_t* __restrict__ Vt, const uint32_t* __restrict__ zrow,
    const float* __restrict__ fmL, const float* __restrict__ bias,
    float* __restrict__ out) {
  int bid = blockIdx.x;
  int bh = bid & 15, qtile = bid >> 4;   // bid%8 const per bh -> same XCD
  int b = bh >> 3, h = bh & 7;
  int q0 = qtile * 32;
  int t = threadIdx.x;
  int w = t >> 6, l = t & 63, lo = l & 15, g = l >> 4;

  __shared__ __align__(16) char smem[32768];
  uint16_t* KsB = (uint16_t*)smem;             // [2][64 k][64 d] 16 KB
  uint16_t* VsB = (uint16_t*)(smem + 16384);   // [2][64 d][64 k] 16 KB

  const uint16_t* Qh = Qb + (size_t)bh * S_ * DK_;
  const uint16_t* Kh = Kb + (size_t)bh * S_ * DK_;
  const uint16_t* Vh = Vt + (size_t)bh * DK_ * S_;

  // DMA: lane l -> LDS row w*16 + l/8, seg l&7; global seg = (l&7)^(row&7).
  int lrow = l >> 3, lseg = (l & 7) ^ lrow;
  const uint16_t* kbase = Kh + (size_t)(w * 16 + lrow) * DK_ + lseg * 8;
  const uint16_t* vbase = Vh + (size_t)(w * 16 + lrow) * S_ + lseg * 8;
  uint16_t* kd0 = KsB + (w * 16) * 64;
  uint16_t* kd8 = KsB + (w * 16 + 8) * 64;
  uint16_t* vd0 = VsB + (w * 16) * 64;
  uint16_t* vd8 = VsB + (w * 16 + 8) * 64;

  // block-uniform zero-bias mask (OR over this block's 32 q rows)
  uint32_t zall = zrow[(b << 11) + q0 + (l & 31)];
#pragma unroll
  for (int s = 1; s < 32; s <<= 1) zall |= __shfl_xor(zall, s);

  // Register-resident Q fragments (B-operand of QK), 2 q-subtiles x K=64.
  bf16x8 qf[2][2];
#pragma unroll
  for (int qt = 0; qt < 2; qt++)
#pragma unroll
    for (int kk = 0; kk < 2; kk++)
      qf[qt][kk] = *(const bf16x8*)(Qh + (size_t)(q0 + qt * 16 + lo) * DK_ + kk * 32 + g * 8);

  f32x4 o[4][2];
#pragma unroll
  for (int dt = 0; dt < 4; dt++)
#pragma unroll
    for (int qt = 0; qt < 2; qt++) o[dt][qt] = (f32x4){0.f, 0.f, 0.f, 0.f};
  float ts[2] = {0.f, 0.f};

  const float* fmrow = fmL + b * S_ + w * 16 + g * 4;
  const float LOG2E = 1.44269504088896340736f;

  // stage tile 0
  cp16(kbase, kd0);
  cp16(kbase + 512, kd8);
  cp16(vbase, vd0);
  cp16(vbase + 8 * S_, vd8);

  for (int kb = 0; kb < 32; kb++) {
    int cur = kb & 1;
    int k0 = kb * 64;
    float4 mv4 = *(const float4*)(fmrow + k0);
    __syncthreads();                             // drains DMA for tile kb
    if (kb + 1 < 32) {                           // prefetch tile kb+1
      int kn = k0 + 64;
      int nb = (cur ^ 1) * 4096;
      cp16(kbase + (size_t)kn * 64, kd0 + nb);
      cp16(kbase + (size_t)kn * 64 + 512, kd8 + nb);
      cp16(vbase + kn, vd0 + nb);
      cp16(vbase + kn + 8 * S_, vd8 + nb);
    }
    const uint16_t* KsT = KsB + cur * 4096;
    const uint16_t* VsT = VsB + cur * 4096;

    // V^T A-frags for PV
    s16x4 vf[4];
    {
      int s = (2 * w + (g >> 1)) ^ (lo & 7);
      int off = s * 8 + (g & 1) * 4;
#pragma unroll
      for (int dt = 0; dt < 4; dt++)
        vf[dt] = *(const s16x4*)(VsT + (dt * 16 + lo) * 64 + off);
    }
    // K A-frags (this wave's 16 k-rows)
    bf16x8 kf[2];
#pragma unroll
    for (int kk = 0; kk < 2; kk++) {
      int s = (kk * 4 + g) ^ (lo & 7);
      kf[kk] = *(const bf16x8*)(KsT + (w * 16 + lo) * 64 + s * 8);
    }

    // S^T = K * Q^T : lane holds S[k = w*16+g*4+r][q = qt*16+lo]
    f32x4 c[2];
#pragma unroll
    for (int qt = 0; qt < 2; qt++) {
      f32x4 z = {0.f, 0.f, 0.f, 0.f};
      z = __builtin_amdgcn_mfma_f32_16x16x32_bf16(kf[0], qf[qt][0], z, 0, 0, 0);
      c[qt] = __builtin_amdgcn_mfma_f32_16x16x32_bf16(kf[1], qf[qt][1], z, 0, 0, 0);
    }

    float p[2][4];
    if (((zall >> kb) & 1u) == 0u) {   // no zero bias in this 64k chunk
#pragma unroll
      for (int qt = 0; qt < 2; qt++) {
        p[qt][0] = __builtin_amdgcn_exp2f(__builtin_fmaf(c[qt][0], LOG2E, mv4.x));
        p[qt][1] = __builtin_amdgcn_exp2f(__builtin_fmaf(c[qt][1], LOG2E, mv4.y));
        p[qt][2] = __builtin_amdgcn_exp2f(__builtin_fmaf(c[qt][2], LOG2E, mv4.z));
        p[qt][3] = __builtin_amdgcn_exp2f(__builtin_fmaf(c[qt][3], LOG2E, mv4.w));
      }
    } else {                           // rare: bias==0 -> weight 0
#pragma unroll
      for (int qt = 0; qt < 2; qt++) {
        float4 bz = *(const float4*)(bias + ((size_t)(b * S_ + q0 + qt * 16 + lo)) * S_ + k0 + w * 16 + g * 4);
        p[qt][0] = (bz.x == 0.f) ? 0.f : __builtin_amdgcn_exp2f(__builtin_fmaf(c[qt][0], LOG2E, mv4.x));
        p[qt][1] = (bz.y == 0.f) ? 0.f : __builtin_amdgcn_exp2f(__builtin_fmaf(c[qt][1], LOG2E, mv4.y));
        p[qt][2] = (bz.z == 0.f) ? 0.f : __builtin_amdgcn_exp2f(__builtin_fmaf(c[qt][2], LOG2E, mv4.z));
        p[qt][3] = (bz.w == 0.f) ? 0.f : __builtin_amdgcn_exp2f(__builtin_fmaf(c[qt][3], LOG2E, mv4.w));
      }
    }

    s16x4 pf[2];
#pragma unroll
    for (int qt = 0; qt < 2; qt++) {
      ts[qt] += (p[qt][0] + p[qt][1]) + (p[qt][2] + p[qt][3]);
      union { s16x4 v; uint32_t u[2]; } uu;
      uu.u[0] = pk2(p[qt][0], p[qt][1]);
      uu.u[1] = pk2(p[qt][2], p[qt][3]);
      pf[qt] = uu.v;
    }

    // PV: o[dt][qt] lane holds O[q=qt*16+lo][d=dt*16+g*4+r]
#pragma unroll
    for (int dt = 0; dt < 4; dt++)
#pragma unroll
      for (int qt = 0; qt < 2; qt++)
        o[dt][qt] = mfma_k16(vf[dt], pf[qt], o[dt][qt]);
  }

  // ---- epilogue: reduce 4 wave-partials, normalize, store ----
  float* OT = (float*)smem;               // [64 d][33] floats (8448 B)
  float* LS = (float*)(smem + 8448);      // [4 w][2 qt][16 lo]
#pragma unroll
  for (int qt = 0; qt < 2; qt++) {
    float v = ts[qt];
    v += __shfl_xor(v, 16);
    v += __shfl_xor(v, 32);
    ts[qt] = v;
  }
  __syncthreads();                        // main-loop LDS reads complete
  if (g == 0) {
#pragma unroll
    for (int qt = 0; qt < 2; qt++) LS[(w * 2 + qt) * 16 + lo] = ts[qt];
  }
#pragma unroll
  for (int ww = 0; ww < 4; ww++) {
    if (w == ww) {
#pragma unroll
      for (int dt = 0; dt < 4; dt++)
#pragma unroll
        for (int qt = 0; qt < 2; qt++)
#pragma unroll
          for (int r = 0; r < 4; r++) {
            int idx = (dt * 16 + g * 4 + r) * 33 + qt * 16 + lo;
            if (ww == 0) OT[idx] = o[dt][qt][r];
            else         OT[idx] += o[dt][qt][r];
          }
    }
    __syncthreads();
  }
  {
    int q = t >> 3, dseg = (t & 7) * 8;   // q in [0,32), 8 d per thread
    int qt2 = q >> 4, lo2 = q & 15;
    float lsum = LS[(0 * 2 + qt2) * 16 + lo2] + LS[(1 * 2 + qt2) * 16 + lo2] +
                 LS[(2 * 2 + qt2) * 16 + lo2] + LS[(3 * 2 + qt2) * 16 + lo2];
    float linv = 1.0f / fmaxf(lsum, 1e-30f);
    float* ob = out + ((size_t)(b * S_ + q0 + q)) * H_ + h * DK_ + dseg;
#pragma unroll
    for (int i = 0; i < 2; i++) {
      float4 v;
      v.x = OT[(dseg + i * 4 + 0) * 33 + q] * linv;
      v.y = OT[(dseg + i * 4 + 1) * 33 + q] * linv;
      v.z = OT[(dseg + i * 4 + 2) * 33 + q] * linv;
      v.w = OT[(dseg + i * 4 + 3) * 33 + q] * linv;
      *(float4*)(ob + i * 4) = v;
    }
  }
}

// ---------------------------------------------------------------------------
extern "C" void kernel_launch(void* const* d_in, const int* in_sizes, int n_in,
                              void* d_out, int out_size, void* d_ws, size_t ws_size,
                              hipStream_t stream) {
  const float* query = (const float*)d_in[0];
  const float* key   = (const float*)d_in[1];
  const float* value = (const float*)d_in[2];
  const float* bias  = (const float*)d_in[3];
  const int*   mask  = (const int*)d_in[4];
  const float* Wq = (const float*)d_in[5];
  const float* bq = (const float*)d_in[6];
  const float* Wk = (const float*)d_in[7];
  const float* bk = (const float*)d_in[8];
  const float* Wv = (const float*)d_in[9];
  const float* bv = (const float*)d_in[10];

  char* ws = (char*)d_ws;
  uint32_t* zrow = (uint32_t*)ws;                             // 16 KB
  float*    fmL  = (float*)(ws + 16384);                      // 16 KB
  uint16_t* Qb = (uint16_t*)(ws + (size_t)(1 << 20));         // 4 MB
  uint16_t* Kb = (uint16_t*)(ws + (size_t)(5 << 20));         // 4 MB
  uint16_t* Vt = (uint16_t*)(ws + (size_t)(9 << 20));         // 4 MB

  ProjArgs pa;
  pa.X[0] = query; pa.X[1] = key; pa.X[2] = value;
  pa.W[0] = Wq;    pa.W[1] = Wk;  pa.W[2] = Wv;
  pa.Bv[0] = bq;   pa.Bv[1] = bk; pa.Bv[2] = bv;
  pa.O[0] = Qb;    pa.O[1] = Kb;  pa.O[2] = Vt;
  pa.bias = bias;  pa.mask = mask;
  pa.zrow = zrow;  pa.fmL = fmL;

  prep_proj_kernel<<<4865, 256, 0, stream>>>(pa);

  attn_kernel<<<1024, 256, 0, stream>>>(Qb, Kb, Vt, zrow, fmL, bias, (float*)d_out);
}

// Round 7
// 173.062 us; speedup vs baseline: 1.3475x; 1.0018x over previous
//
#include <hip/hip_runtime.h>
#include <hip/hip_bf16.h>
#include <stdint.h>

#define B_  2
#define S_  2048
#define H_  512
#define NH_ 8
#define DK_ 64

typedef __bf16 bf16x8 __attribute__((ext_vector_type(8)));
typedef short  s16x4  __attribute__((ext_vector_type(4)));
typedef float  f32x4  __attribute__((ext_vector_type(4)));

static __device__ __forceinline__ uint32_t pk2(float a, float b) {
  __hip_bfloat162 h = __float22bfloat162_rn(float2{a, b});
  uint32_t u;
  __builtin_memcpy(&u, &h, 4);
  return u;
}
static __device__ __forceinline__ uint4 pkf8(float4 a, float4 b) {
  return uint4{pk2(a.x, a.y), pk2(a.z, a.w), pk2(b.x, b.y), pk2(b.z, b.w)};
}

// 16x16x16 bf16 MFMA. Guard with __HIP_DEVICE_COMPILE__ (host pass lacks
// device builtins — R3 compile failure).
static __device__ __forceinline__ f32x4 mfma_k16(s16x4 a, s16x4 b, f32x4 c) {
#if defined(__HIP_DEVICE_COMPILE__)
  return __builtin_amdgcn_mfma_f32_16x16x16bf16_1k(a, b, c, 0, 0, 0);
#else
  (void)a; (void)b;
  return c;
#endif
}

typedef const __attribute__((address_space(1))) uint32_t* gas_t;
typedef __attribute__((address_space(3))) uint32_t* las_t;
static __device__ __forceinline__ void cp16(const void* g, void* l) {
  __builtin_amdgcn_global_load_lds((gas_t)g, (las_t)l, 16, 0, 0);
}

// ---------------------------------------------------------------------------
// Kernel 1 (fused): proj (blocks 0..767, XCD-swizzled so the 8 dtile-blocks
// sharing one X m-tile land on ONE XCD's L2 — R6 showed 116 MB FETCH from
// cross-XCD X re-fetch) + bias zero-scan (768..1279, 8 rows/block, 16 loads
// in flight) + fmL (1280).
// ---------------------------------------------------------------------------
struct ProjArgs {
  const float* X[3];
  const float* W[3];
  const float* Bv[3];
  uint16_t*    O[3];
  const float* bias;
  const int*   mask;
  uint32_t*    zrow;
  float*       fmL;
};

__global__ __launch_bounds__(256) void prep_proj_kernel(ProjArgs pa) {
  __shared__ __align__(16) char psm[24640];
  int bid = blockIdx.x, t = threadIdx.x;

  if (bid >= 768) {
    if (bid < 1280) {
      // ---- bias zero-scan: 8 (b,q) rows per block, loads pipelined ----
      int rr = bid - 768;                      // 0..511
      const float* base = pa.bias + (size_t)rr * 8 * 2048 + t * 8;
      uint4 a[8], b2[8];
#pragma unroll
      for (int i = 0; i < 8; i++) {
        const uint4* src = (const uint4*)(base + (size_t)i * 2048);
        a[i] = src[0]; b2[i] = src[1];
      }
      uint32_t (*wbuf)[4] = (uint32_t (*)[4])psm;   // [row][wave]
      int wv = t >> 6, ln = t & 63;
#pragma unroll
      for (int i = 0; i < 8; i++) {
        bool z = ((a[i].x << 1) == 0u) | ((a[i].y << 1) == 0u) |
                 ((a[i].z << 1) == 0u) | ((a[i].w << 1) == 0u) |
                 ((b2[i].x << 1) == 0u) | ((b2[i].y << 1) == 0u) |
                 ((b2[i].z << 1) == 0u) | ((b2[i].w << 1) == 0u);
        uint64_t m = __ballot(z);
        if (ln == 0) {
          uint32_t bits = 0;
#pragma unroll
          for (int c = 0; c < 8; c++)
            bits |= (uint32_t)(((m >> (8 * c)) & 0xFFull) != 0ull) << c;
          wbuf[i][wv] = bits;                  // chunks [wv*8, wv*8+8)
        }
      }
      __syncthreads();
      if (t < 8)
        pa.zrow[rr * 8 + t] = wbuf[t][0] | (wbuf[t][1] << 8) |
                              (wbuf[t][2] << 16) | (wbuf[t][3] << 24);
    } else {
      // ---- fmL = mask * log2(e) ----
      const float LOG2E = 1.44269504088896340736f;
#pragma unroll
      for (int i = 0; i < 16; i++) {
        int idx = i * 256 + t;
        pa.fmL[idx] = (float)pa.mask[idx] * LOG2E;
      }
    }
    return;
  }

  // ---- proj: y = x @ W^T + b, tile 128 s x 64 d ----
  // XCD swizzle: all 8 dtiles of group gi=(mat,mtile) get bids == gi (mod 8)
  // -> same XCD -> X tile fetched into one L2, read 8x from there.
  int xcd = bid & 7, j = bid >> 3;             // j in 0..95
  int gi = ((j >> 3) << 3) | xcd;              // group 0..95
  int dtile = j & 7;
  int mat = gi >> 5, mtile = gi & 31;
  int m0 = mtile * 128, n0 = dtile * 64;
  const float* X  = pa.X[mat];
  const float* Wt = pa.W[mat];
  const float* Bv = pa.Bv[mat];
  uint16_t*    O  = pa.O[mat];

  uint16_t (*Xs)[64] = (uint16_t (*)[64])psm;             // [128][64] 16 KB
  uint16_t (*Ws)[64] = (uint16_t (*)[64])(psm + 16384);   // [64][64]   8 KB

  int w = t >> 6, l = t & 63, lo = l & 15, g = l >> 4;
  int srow = t >> 1, shalf = t & 1;
  int wrow = t >> 2, wq = t & 3;

  const float* Xrow = X + (size_t)(m0 + srow) * 512 + shalf * 32;
  const float* Wrow = Wt + (size_t)(n0 + wrow) * 512 + wq * 16;

  f32x4 acc[2][4];
#pragma unroll
  for (int st = 0; st < 2; st++)
#pragma unroll
    for (int dt = 0; dt < 4; dt++) acc[st][dt] = (f32x4){0.f, 0.f, 0.f, 0.f};

  float4 xa[8], wa2[4];
  {
    const float4* sx = (const float4*)Xrow;
    const float4* sw = (const float4*)Wrow;
#pragma unroll
    for (int i = 0; i < 8; i++) xa[i] = sx[i];
#pragma unroll
    for (int i = 0; i < 4; i++) wa2[i] = sw[i];
  }

  for (int kb = 0; kb < 8; kb++) {
#pragma unroll
    for (int j2 = 0; j2 < 4; j2++) {
      int s = (shalf * 4 + j2) ^ (srow & 7);
      *(uint4*)&Xs[srow][s * 8] = pkf8(xa[2 * j2], xa[2 * j2 + 1]);
    }
#pragma unroll
    for (int j2 = 0; j2 < 2; j2++) {
      int s = (wq * 2 + j2) ^ (wrow & 7);
      *(uint4*)&Ws[wrow][s * 8] = pkf8(wa2[2 * j2], wa2[2 * j2 + 1]);
    }
    __syncthreads();
    if (kb < 7) {
      const float4* sx = (const float4*)(Xrow + (kb + 1) * 64);
      const float4* sw = (const float4*)(Wrow + (kb + 1) * 64);
#pragma unroll
      for (int i = 0; i < 8; i++) xa[i] = sx[i];
#pragma unroll
      for (int i = 0; i < 4; i++) wa2[i] = sw[i];
    }
#pragma unroll
    for (int kk = 0; kk < 2; kk++) {
      int seg = (kk * 4 + g) ^ (lo & 7);
      bf16x8 xf[2], wf[4];
#pragma unroll
      for (int st = 0; st < 2; st++)
        xf[st] = *(const bf16x8*)&Xs[w * 32 + st * 16 + lo][seg * 8];
#pragma unroll
      for (int dt = 0; dt < 4; dt++)
        wf[dt] = *(const bf16x8*)&Ws[dt * 16 + lo][seg * 8];
      if (mat < 2) {
#pragma unroll
        for (int st = 0; st < 2; st++)
#pragma unroll
          for (int dt = 0; dt < 4; dt++)
            acc[st][dt] = __builtin_amdgcn_mfma_f32_16x16x32_bf16(wf[dt], xf[st], acc[st][dt], 0, 0, 0);
      } else {
#pragma unroll
        for (int st = 0; st < 2; st++)
#pragma unroll
          for (int dt = 0; dt < 4; dt++)
            acc[st][dt] = __builtin_amdgcn_mfma_f32_16x16x32_bf16(xf[st], wf[dt], acc[st][dt], 0, 0, 0);
      }
    }
    __syncthreads();
  }

  if (mat < 2) {
    float scale = (mat == 0) ? 0.125f : 1.0f;
    float4 bv4[4];
#pragma unroll
    for (int dt = 0; dt < 4; dt++)
      bv4[dt] = *(const float4*)(Bv + n0 + dt * 16 + g * 4);
#pragma unroll
    for (int st = 0; st < 2; st++) {
      int ss = m0 + w * 32 + st * 16 + lo;
      int bb = ss >> 11, sIn = ss & 2047;
      uint16_t* obase = O + ((size_t)(bb * NH_ + dtile) * S_ + sIn) * DK_;
#pragma unroll
      for (int dt = 0; dt < 4; dt++) {
        float v0 = (acc[st][dt][0] + bv4[dt].x) * scale;
        float v1 = (acc[st][dt][1] + bv4[dt].y) * scale;
        float v2 = (acc[st][dt][2] + bv4[dt].z) * scale;
        float v3 = (acc[st][dt][3] + bv4[dt].w) * scale;
        uint2 pk{pk2(v0, v1), pk2(v2, v3)};
        *(uint2*)(obase + dt * 16 + g * 4) = pk;
      }
    }
  } else {
    float bval[4];
#pragma unroll
    for (int dt = 0; dt < 4; dt++) bval[dt] = Bv[n0 + dt * 16 + lo];
#pragma unroll
    for (int st = 0; st < 2; st++) {
      int m = m0 + w * 32 + st * 16 + g * 4;
      int bb = m >> 11, sIn = m & 2047;
#pragma unroll
      for (int dt = 0; dt < 4; dt++) {
        int dd = dt * 16 + lo;
        float v0 = acc[st][dt][0] + bval[dt];
        float v1 = acc[st][dt][1] + bval[dt];
        float v2 = acc[st][dt][2] + bval[dt];
        float v3 = acc[st][dt][3] + bval[dt];
        uint2 pk{pk2(v0, v1), pk2(v2, v3)};
        *(uint2*)(O + ((size_t)(bb * NH_ + dtile) * DK_ + dd) * S_ + sIn) = pk;
      }
    }
  }
}

// ---------------------------------------------------------------------------
// Kernel 2: flash attention (unchanged from R6 — verified). 256 thr, 4 waves,
// k-tile 64, q-tile 32 -> grid 1024 -> 4 blocks/CU = 16 waves/CU, no spills.
// R5 lesson: never buy occupancy with a VGPR cap below the live footprint.
// ---------------------------------------------------------------------------
__global__ __launch_bounds__(256, 2) void attn_kernel(
    const uint16_t* __restrict__ Qb, const uint16_t* __restrict__ Kb,
    const uint16_t* __restrict__ Vt, const uint32_t* __restrict__ zrow,
    const float* __restrict__ fmL, const float* __restrict__ bias,
    float* __restrict__ out) {
  int bid = blockIdx.x;
  int bh = bid & 15, qtile = bid >> 4;   // bid%8 const per bh -> same XCD
  int b = bh >> 3, h = bh & 7;
  int q0 = qtile * 32;
  int t = threadIdx.x;
  int w = t >> 6, l = t & 63, lo = l & 15, g = l >> 4;

  __shared__ __align__(16) char smem[32768];
  uint16_t* KsB = (uint16_t*)smem;             // [2][64 k][64 d] 16 KB
  uint16_t* VsB = (uint16_t*)(smem + 16384);   // [2][64 d][64 k] 16 KB

  const uint16_t* Qh = Qb + (size_t)bh * S_ * DK_;
  const uint16_t* Kh = Kb + (size_t)bh * S_ * DK_;
  const uint16_t* Vh = Vt + (size_t)bh * DK_ * S_;

  // DMA: lane l -> LDS row w*16 + l/8, seg l&7; global seg = (l&7)^(row&7).
  int lrow = l >> 3, lseg = (l & 7) ^ lrow;
  const uint16_t* kbase = Kh + (size_t)(w * 16 + lrow) * DK_ + lseg * 8;
  const uint16_t* vbase = Vh + (size_t)(w * 16 + lrow) * S_ + lseg * 8;
  uint16_t* kd0 = KsB + (w * 16) * 64;
  uint16_t* kd8 = KsB + (w * 16 + 8) * 64;
  uint16_t* vd0 = VsB + (w * 16) * 64;
  uint16_t* vd8 = VsB + (w * 16 + 8) * 64;

  // block-uniform zero-bias mask (OR over this block's 32 q rows)
  uint32_t zall = zrow[(b << 11) + q0 + (l & 31)];
#pragma unroll
  for (int s = 1; s < 32; s <<= 1) zall |= __shfl_xor(zall, s);

  // Register-resident Q fragments (B-operand of QK), 2 q-subtiles x K=64.
  bf16x8 qf[2][2];
#pragma unroll
  for (int qt = 0; qt < 2; qt++)
#pragma unroll
    for (int kk = 0; kk < 2; kk++)
      qf[qt][kk] = *(const bf16x8*)(Qh + (size_t)(q0 + qt * 16 + lo) * DK_ + kk * 32 + g * 8);

  f32x4 o[4][2];
#pragma unroll
  for (int dt = 0; dt < 4; dt++)
#pragma unroll
    for (int qt = 0; qt < 2; qt++) o[dt][qt] = (f32x4){0.f, 0.f, 0.f, 0.f};
  float ts[2] = {0.f, 0.f};

  const float* fmrow = fmL + b * S_ + w * 16 + g * 4;
  const float LOG2E = 1.44269504088896340736f;

  // stage tile 0
  cp16(kbase, kd0);
  cp16(kbase + 512, kd8);
  cp16(vbase, vd0);
  cp16(vbase + 8 * S_, vd8);

  for (int kb = 0; kb < 32; kb++) {
    int cur = kb & 1;
    int k0 = kb * 64;
    float4 mv4 = *(const float4*)(fmrow + k0);
    __syncthreads();                             // drains DMA for tile kb
    if (kb + 1 < 32) {                           // prefetch tile kb+1
      int kn = k0 + 64;
      int nb = (cur ^ 1) * 4096;
      cp16(kbase + (size_t)kn * 64, kd0 + nb);
      cp16(kbase + (size_t)kn * 64 + 512, kd8 + nb);
      cp16(vbase + kn, vd0 + nb);
      cp16(vbase + kn + 8 * S_, vd8 + nb);
    }
    const uint16_t* KsT = KsB + cur * 4096;
    const uint16_t* VsT = VsB + cur * 4096;

    // V^T A-frags for PV
    s16x4 vf[4];
    {
      int s = (2 * w + (g >> 1)) ^ (lo & 7);
      int off = s * 8 + (g & 1) * 4;
#pragma unroll
      for (int dt = 0; dt < 4; dt++)
        vf[dt] = *(const s16x4*)(VsT + (dt * 16 + lo) * 64 + off);
    }
    // K A-frags (this wave's 16 k-rows)
    bf16x8 kf[2];
#pragma unroll
    for (int kk = 0; kk < 2; kk++) {
      int s = (kk * 4 + g) ^ (lo & 7);
      kf[kk] = *(const bf16x8*)(KsT + (w * 16 + lo) * 64 + s * 8);
    }

    // S^T = K * Q^T : lane holds S[k = w*16+g*4+r][q = qt*16+lo]
    f32x4 c[2];
#pragma unroll
    for (int qt = 0; qt < 2; qt++) {
      f32x4 z = {0.f, 0.f, 0.f, 0.f};
      z = __builtin_amdgcn_mfma_f32_16x16x32_bf16(kf[0], qf[qt][0], z, 0, 0, 0);
      c[qt] = __builtin_amdgcn_mfma_f32_16x16x32_bf16(kf[1], qf[qt][1], z, 0, 0, 0);
    }

    float p[2][4];
    if (((zall >> kb) & 1u) == 0u) {   // no zero bias in this 64k chunk
#pragma unroll
      for (int qt = 0; qt < 2; qt++) {
        p[qt][0] = __builtin_amdgcn_exp2f(__builtin_fmaf(c[qt][0], LOG2E, mv4.x));
        p[qt][1] = __builtin_amdgcn_exp2f(__builtin_fmaf(c[qt][1], LOG2E, mv4.y));
        p[qt][2] = __builtin_amdgcn_exp2f(__builtin_fmaf(c[qt][2], LOG2E, mv4.z));
        p[qt][3] = __builtin_amdgcn_exp2f(__builtin_fmaf(c[qt][3], LOG2E, mv4.w));
      }
    } else {                           // rare: bias==0 -> weight 0
#pragma unroll
      for (int qt = 0; qt < 2; qt++) {
        float4 bz = *(const float4*)(bias + ((size_t)(b * S_ + q0 + qt * 16 + lo)) * S_ + k0 + w * 16 + g * 4);
        p[qt][0] = (bz.x == 0.f) ? 0.f : __builtin_amdgcn_exp2f(__builtin_fmaf(c[qt][0], LOG2E, mv4.x));
        p[qt][1] = (bz.y == 0.f) ? 0.f : __builtin_amdgcn_exp2f(__builtin_fmaf(c[qt][1], LOG2E, mv4.y));
        p[qt][2] = (bz.z == 0.f) ? 0.f : __builtin_amdgcn_exp2f(__builtin_fmaf(c[qt][2], LOG2E, mv4.z));
        p[qt][3] = (bz.w == 0.f) ? 0.f : __builtin_amdgcn_exp2f(__builtin_fmaf(c[qt][3], LOG2E, mv4.w));
      }
    }

    s16x4 pf[2];
#pragma unroll
    for (int qt = 0; qt < 2; qt++) {
      ts[qt] += (p[qt][0] + p[qt][1]) + (p[qt][2] + p[qt][3]);
      union { s16x4 v; uint32_t u[2]; } uu;
      uu.u[0] = pk2(p[qt][0], p[qt][1]);
      uu.u[1] = pk2(p[qt][2], p[qt][3]);
      pf[qt] = uu.v;
    }

    // PV: o[dt][qt] lane holds O[q=qt*16+lo][d=dt*16+g*4+r]
#pragma unroll
    for (int dt = 0; dt < 4; dt++)
#pragma unroll
      for (int qt = 0; qt < 2; qt++)
        o[dt][qt] = mfma_k16(vf[dt], pf[qt], o[dt][qt]);
  }

  // ---- epilogue: reduce 4 wave-partials, normalize, store ----
  float* OT = (float*)smem;               // [64 d][33] floats (8448 B)
  float* LS = (float*)(smem + 8448);      // [4 w][2 qt][16 lo]
#pragma unroll
  for (int qt = 0; qt < 2; qt++) {
    float v = ts[qt];
    v += __shfl_xor(v, 16);
    v += __shfl_xor(v, 32);
    ts[qt] = v;
  }
  __syncthreads();                        // main-loop LDS reads complete
  if (g == 0) {
#pragma unroll
    for (int qt = 0; qt < 2; qt++) LS[(w * 2 + qt) * 16 + lo] = ts[qt];
  }
#pragma unroll
  for (int ww = 0; ww < 4; ww++) {
    if (w == ww) {
#pragma unroll
      for (int dt = 0; dt < 4; dt++)
#pragma unroll
        for (int qt = 0; qt < 2; qt++)
#pragma unroll
          for (int r = 0; r < 4; r++) {
            int idx = (dt * 16 + g * 4 + r) * 33 + qt * 16 + lo;
            if (ww == 0) OT[idx] = o[dt][qt][r];
            else         OT[idx] += o[dt][qt][r];
          }
    }
    __syncthreads();
  }
  {
    int q = t >> 3, dseg = (t & 7) * 8;   // q in [0,32), 8 d per thread
    int qt2 = q >> 4, lo2 = q & 15;
    float lsum = LS[(0 * 2 + qt2) * 16 + lo2] + LS[(1 * 2 + qt2) * 16 + lo2] +
                 LS[(2 * 2 + qt2) * 16 + lo2] + LS[(3 * 2 + qt2) * 16 + lo2];
    float linv = 1.0f / fmaxf(lsum, 1e-30f);
    float* ob = out + ((size_t)(b * S_ + q0 + q)) * H_ + h * DK_ + dseg;
#pragma unroll
    for (int i = 0; i < 2; i++) {
      float4 v;
      v.x = OT[(dseg + i * 4 + 0) * 33 + q] * linv;
      v.y = OT[(dseg + i * 4 + 1) * 33 + q] * linv;
      v.z = OT[(dseg + i * 4 + 2) * 33 + q] * linv;
      v.w = OT[(dseg + i * 4 + 3) * 33 + q] * linv;
      *(float4*)(ob + i * 4) = v;
    }
  }
}

// ---------------------------------------------------------------------------
extern "C" void kernel_launch(void* const* d_in, const int* in_sizes, int n_in,
                              void* d_out, int out_size, void* d_ws, size_t ws_size,
                              hipStream_t stream) {
  const float* query = (const float*)d_in[0];
  const float* key   = (const float*)d_in[1];
  const float* value = (const float*)d_in[2];
  const float* bias  = (const float*)d_in[3];
  const int*   mask  = (const int*)d_in[4];
  const float* Wq = (const float*)d_in[5];
  const float* bq = (const float*)d_in[6];
  const float* Wk = (const float*)d_in[7];
  const float* bk = (const float*)d_in[8];
  const float* Wv = (const float*)d_in[9];
  const float* bv = (const float*)d_in[10];

  char* ws = (char*)d_ws;
  uint32_t* zrow = (uint32_t*)ws;                             // 16 KB
  float*    fmL  = (float*)(ws + 16384);                      // 16 KB
  uint16_t* Qb = (uint16_t*)(ws + (size_t)(1 << 20));         // 4 MB
  uint16_t* Kb = (uint16_t*)(ws + (size_t)(5 << 20));         // 4 MB
  uint16_t* Vt = (uint16_t*)(ws + (size_t)(9 << 20));         // 4 MB

  ProjArgs pa;
  pa.X[0] = query; pa.X[1] = key; pa.X[2] = value;
  pa.W[0] = Wq;    pa.W[1] = Wk;  pa.W[2] = Wv;
  pa.Bv[0] = bq;   pa.Bv[1] = bk; pa.Bv[2] = bv;
  pa.O[0] = Qb;    pa.O[1] = Kb;  pa.O[2] = Vt;
  pa.bias = bias;  pa.mask = mask;
  pa.zrow = zrow;  pa.fmL = fmL;

  prep_proj_kernel<<<1281, 256, 0, stream>>>(pa);

  attn_kernel<<<1024, 256, 0, stream>>>(Qb, Kb, Vt, zrow, fmL, bias, (float*)d_out);
}

// Round 8
// 160.713 us; speedup vs baseline: 1.4511x; 1.0768x over previous
//
#include <hip/hip_runtime.h>
#include <hip/hip_bf16.h>
#include <stdint.h>

#define B_  2
#define S_  2048
#define H_  512
#define NH_ 8
#define DK_ 64

typedef __bf16 bf16x8 __attribute__((ext_vector_type(8)));
typedef short  s16x4  __attribute__((ext_vector_type(4)));
typedef float  f32x4  __attribute__((ext_vector_type(4)));

static __device__ __forceinline__ uint32_t pk2(float a, float b) {
  __hip_bfloat162 h = __float22bfloat162_rn(float2{a, b});
  uint32_t u;
  __builtin_memcpy(&u, &h, 4);
  return u;
}

// 16x16x16 bf16 MFMA. Guard with __HIP_DEVICE_COMPILE__ (host pass lacks
// device builtins — R3 compile failure).
static __device__ __forceinline__ f32x4 mfma_k16(s16x4 a, s16x4 b, f32x4 c) {
#if defined(__HIP_DEVICE_COMPILE__)
  return __builtin_amdgcn_mfma_f32_16x16x16bf16_1k(a, b, c, 0, 0, 0);
#else
  (void)a; (void)b;
  return c;
#endif
}

typedef const __attribute__((address_space(1))) uint32_t* gas_t;
typedef __attribute__((address_space(3))) uint32_t* las_t;
static __device__ __forceinline__ void cp16(const void* g, void* l) {
  __builtin_amdgcn_global_load_lds((gas_t)g, (las_t)l, 16, 0, 0);
}

// ---------------------------------------------------------------------------
// Kernel 1 (fused): proj (blocks 0..767, XCD-swizzled for X reuse in L2) +
// bias zero-scan (768..1279) + fmL (1280).
// R7 fix: staging loads re-mapped for coalescing — 16 lanes per 256 B row
// segment (was 2 lanes/row => 64 cache-line touches per instruction).
// ---------------------------------------------------------------------------
struct ProjArgs {
  const float* X[3];
  const float* W[3];
  const float* Bv[3];
  uint16_t*    O[3];
  const float* bias;
  const int*   mask;
  uint32_t*    zrow;
  float*       fmL;
};

__global__ __launch_bounds__(256) void prep_proj_kernel(ProjArgs pa) {
  __shared__ __align__(16) char psm[24640];
  int bid = blockIdx.x, t = threadIdx.x;

  if (bid >= 768) {
    if (bid < 1280) {
      // ---- bias zero-scan: 8 (b,q) rows per block, loads pipelined ----
      int rr = bid - 768;                      // 0..511
      const float* base = pa.bias + (size_t)rr * 8 * 2048 + t * 8;
      uint4 a[8], b2[8];
#pragma unroll
      for (int i = 0; i < 8; i++) {
        const uint4* src = (const uint4*)(base + (size_t)i * 2048);
        a[i] = src[0]; b2[i] = src[1];
      }
      uint32_t (*wbuf)[4] = (uint32_t (*)[4])psm;   // [row][wave]
      int wv = t >> 6, ln = t & 63;
#pragma unroll
      for (int i = 0; i < 8; i++) {
        bool z = ((a[i].x << 1) == 0u) | ((a[i].y << 1) == 0u) |
                 ((a[i].z << 1) == 0u) | ((a[i].w << 1) == 0u) |
                 ((b2[i].x << 1) == 0u) | ((b2[i].y << 1) == 0u) |
                 ((b2[i].z << 1) == 0u) | ((b2[i].w << 1) == 0u);
        uint64_t m = __ballot(z);
        if (ln == 0) {
          uint32_t bits = 0;
#pragma unroll
          for (int c = 0; c < 8; c++)
            bits |= (uint32_t)(((m >> (8 * c)) & 0xFFull) != 0ull) << c;
          wbuf[i][wv] = bits;                  // chunks [wv*8, wv*8+8)
        }
      }
      __syncthreads();
      if (t < 8)
        pa.zrow[rr * 8 + t] = wbuf[t][0] | (wbuf[t][1] << 8) |
                              (wbuf[t][2] << 16) | (wbuf[t][3] << 24);
    } else {
      // ---- fmL = mask * log2(e) ----
      const float LOG2E = 1.44269504088896340736f;
#pragma unroll
      for (int i = 0; i < 16; i++) {
        int idx = i * 256 + t;
        pa.fmL[idx] = (float)pa.mask[idx] * LOG2E;
      }
    }
    return;
  }

  // ---- proj: y = x @ W^T + b, tile 128 s x 64 d ----
  // XCD swizzle: all 8 dtiles of group gi=(mat,mtile) get bids == gi (mod 8)
  // -> same XCD -> X tile fetched into one L2, read 8x from there.
  int xcd = bid & 7, j = bid >> 3;             // j in 0..95
  int gi = ((j >> 3) << 3) | xcd;              // group 0..95
  int dtile = j & 7;
  int mat = gi >> 5, mtile = gi & 31;
  int m0 = mtile * 128, n0 = dtile * 64;
  const float* X  = pa.X[mat];
  const float* Wt = pa.W[mat];
  const float* Bv = pa.Bv[mat];
  uint16_t*    O  = pa.O[mat];

  uint16_t (*Xs)[64] = (uint16_t (*)[64])psm;             // [128][64] 16 KB
  uint16_t (*Ws)[64] = (uint16_t (*)[64])(psm + 16384);   // [64][64]   8 KB

  int w = t >> 6, l = t & 63, lo = l & 15, g = l >> 4;
  int lr = l >> 4;          // 0..3 row-in-group (16 lanes per row)
  int lc = l & 15;          // 16B column chunk within the 256B row segment

  // coalesced staging bases: lane covers float cols [lc*4, lc*4+4)
  const float* Xp = X + (size_t)(m0 + w * 32 + lr) * 512 + lc * 4;
  const float* Wp = Wt + (size_t)(n0 + w * 16 + lr) * 512 + lc * 4;

  f32x4 acc[2][4];
#pragma unroll
  for (int st = 0; st < 2; st++)
#pragma unroll
    for (int dt = 0; dt < 4; dt++) acc[st][dt] = (f32x4){0.f, 0.f, 0.f, 0.f};

  float4 xa[8], wa2[4];
#pragma unroll
  for (int i = 0; i < 8; i++) xa[i] = *(const float4*)(Xp + (size_t)i * 4 * 512);
#pragma unroll
  for (int i = 0; i < 4; i++) wa2[i] = *(const float4*)(Wp + (size_t)i * 4 * 512);

  for (int kb = 0; kb < 8; kb++) {
    // pack current registers -> LDS (bf16), b64 per row-chunk.
    // LDS content identical to prior rounds: row-major, 16B segs XOR'd by row&7.
#pragma unroll
    for (int i = 0; i < 8; i++) {
      int r = w * 32 + i * 4 + lr;
      int s0 = (lc >> 1) ^ (r & 7);
      uint2 pk{pk2(xa[i].x, xa[i].y), pk2(xa[i].z, xa[i].w)};
      *(uint2*)&Xs[r][s0 * 8 + (lc & 1) * 4] = pk;
    }
#pragma unroll
    for (int i = 0; i < 4; i++) {
      int r = w * 16 + i * 4 + lr;
      int s0 = (lc >> 1) ^ (r & 7);
      uint2 pk{pk2(wa2[i].x, wa2[i].y), pk2(wa2[i].z, wa2[i].w)};
      *(uint2*)&Ws[r][s0 * 8 + (lc & 1) * 4] = pk;
    }
    __syncthreads();
    if (kb < 7) {
      const float* Xn = Xp + (kb + 1) * 64;
      const float* Wn = Wp + (kb + 1) * 64;
#pragma unroll
      for (int i = 0; i < 8; i++) xa[i] = *(const float4*)(Xn + (size_t)i * 4 * 512);
#pragma unroll
      for (int i = 0; i < 4; i++) wa2[i] = *(const float4*)(Wn + (size_t)i * 4 * 512);
    }
#pragma unroll
    for (int kk = 0; kk < 2; kk++) {
      int seg = (kk * 4 + g) ^ (lo & 7);
      bf16x8 xf[2], wf[4];
#pragma unroll
      for (int st = 0; st < 2; st++)
        xf[st] = *(const bf16x8*)&Xs[w * 32 + st * 16 + lo][seg * 8];
#pragma unroll
      for (int dt = 0; dt < 4; dt++)
        wf[dt] = *(const bf16x8*)&Ws[dt * 16 + lo][seg * 8];
      if (mat < 2) {
#pragma unroll
        for (int st = 0; st < 2; st++)
#pragma unroll
          for (int dt = 0; dt < 4; dt++)
            acc[st][dt] = __builtin_amdgcn_mfma_f32_16x16x32_bf16(wf[dt], xf[st], acc[st][dt], 0, 0, 0);
      } else {
#pragma unroll
        for (int st = 0; st < 2; st++)
#pragma unroll
          for (int dt = 0; dt < 4; dt++)
            acc[st][dt] = __builtin_amdgcn_mfma_f32_16x16x32_bf16(xf[st], wf[dt], acc[st][dt], 0, 0, 0);
      }
    }
    __syncthreads();
  }

  if (mat < 2) {
    float scale = (mat == 0) ? 0.125f : 1.0f;
    float4 bv4[4];
#pragma unroll
    for (int dt = 0; dt < 4; dt++)
      bv4[dt] = *(const float4*)(Bv + n0 + dt * 16 + g * 4);
#pragma unroll
    for (int st = 0; st < 2; st++) {
      int ss = m0 + w * 32 + st * 16 + lo;
      int bb = ss >> 11, sIn = ss & 2047;
      uint16_t* obase = O + ((size_t)(bb * NH_ + dtile) * S_ + sIn) * DK_;
#pragma unroll
      for (int dt = 0; dt < 4; dt++) {
        float v0 = (acc[st][dt][0] + bv4[dt].x) * scale;
        float v1 = (acc[st][dt][1] + bv4[dt].y) * scale;
        float v2 = (acc[st][dt][2] + bv4[dt].z) * scale;
        float v3 = (acc[st][dt][3] + bv4[dt].w) * scale;
        uint2 pk{pk2(v0, v1), pk2(v2, v3)};
        *(uint2*)(obase + dt * 16 + g * 4) = pk;
      }
    }
  } else {
    float bval[4];
#pragma unroll
    for (int dt = 0; dt < 4; dt++) bval[dt] = Bv[n0 + dt * 16 + lo];
#pragma unroll
    for (int st = 0; st < 2; st++) {
      int m = m0 + w * 32 + st * 16 + g * 4;
      int bb = m >> 11, sIn = m & 2047;
#pragma unroll
      for (int dt = 0; dt < 4; dt++) {
        int dd = dt * 16 + lo;
        float v0 = acc[st][dt][0] + bval[dt];
        float v1 = acc[st][dt][1] + bval[dt];
        float v2 = acc[st][dt][2] + bval[dt];
        float v3 = acc[st][dt][3] + bval[dt];
        uint2 pk{pk2(v0, v1), pk2(v2, v3)};
        *(uint2*)(O + ((size_t)(bb * NH_ + dtile) * DK_ + dd) * S_ + sIn) = pk;
      }
    }
  }
}

// ---------------------------------------------------------------------------
// Kernel 2: flash attention (unchanged — verified). 256 thr, 4 waves, k-tile
// 64, q-tile 32 -> grid 1024 -> 4 blocks/CU = 16 waves/CU, no spills.
// R5 lesson: never buy occupancy with a VGPR cap below the live footprint.
// ---------------------------------------------------------------------------
__global__ __launch_bounds__(256, 2) void attn_kernel(
    const uint16_t* __restrict__ Qb, const uint16_t* __restrict__ Kb,
    const uint16_t* __restrict__ Vt, const uint32_t* __restrict__ zrow,
    const float* __restrict__ fmL, const float* __restrict__ bias,
    float* __restrict__ out) {
  int bid = blockIdx.x;
  int bh = bid & 15, qtile = bid >> 4;   // bid%8 const per bh -> same XCD
  int b = bh >> 3, h = bh & 7;
  int q0 = qtile * 32;
  int t = threadIdx.x;
  int w = t >> 6, l = t & 63, lo = l & 15, g = l >> 4;

  __shared__ __align__(16) char smem[32768];
  uint16_t* KsB = (uint16_t*)smem;             // [2][64 k][64 d] 16 KB
  uint16_t* VsB = (uint16_t*)(smem + 16384);   // [2][64 d][64 k] 16 KB

  const uint16_t* Qh = Qb + (size_t)bh * S_ * DK_;
  const uint16_t* Kh = Kb + (size_t)bh * S_ * DK_;
  const uint16_t* Vh = Vt + (size_t)bh * DK_ * S_;

  // DMA: lane l -> LDS row w*16 + l/8, seg l&7; global seg = (l&7)^(row&7).
  int lrow = l >> 3, lseg = (l & 7) ^ lrow;
  const uint16_t* kbase = Kh + (size_t)(w * 16 + lrow) * DK_ + lseg * 8;
  const uint16_t* vbase = Vh + (size_t)(w * 16 + lrow) * S_ + lseg * 8;
  uint16_t* kd0 = KsB + (w * 16) * 64;
  uint16_t* kd8 = KsB + (w * 16 + 8) * 64;
  uint16_t* vd0 = VsB + (w * 16) * 64;
  uint16_t* vd8 = VsB + (w * 16 + 8) * 64;

  // block-uniform zero-bias mask (OR over this block's 32 q rows)
  uint32_t zall = zrow[(b << 11) + q0 + (l & 31)];
#pragma unroll
  for (int s = 1; s < 32; s <<= 1) zall |= __shfl_xor(zall, s);

  // Register-resident Q fragments (B-operand of QK), 2 q-subtiles x K=64.
  bf16x8 qf[2][2];
#pragma unroll
  for (int qt = 0; qt < 2; qt++)
#pragma unroll
    for (int kk = 0; kk < 2; kk++)
      qf[qt][kk] = *(const bf16x8*)(Qh + (size_t)(q0 + qt * 16 + lo) * DK_ + kk * 32 + g * 8);

  f32x4 o[4][2];
#pragma unroll
  for (int dt = 0; dt < 4; dt++)
#pragma unroll
    for (int qt = 0; qt < 2; qt++) o[dt][qt] = (f32x4){0.f, 0.f, 0.f, 0.f};
  float ts[2] = {0.f, 0.f};

  const float* fmrow = fmL + b * S_ + w * 16 + g * 4;
  const float LOG2E = 1.44269504088896340736f;

  // stage tile 0
  cp16(kbase, kd0);
  cp16(kbase + 512, kd8);
  cp16(vbase, vd0);
  cp16(vbase + 8 * S_, vd8);

  for (int kb = 0; kb < 32; kb++) {
    int cur = kb & 1;
    int k0 = kb * 64;
    float4 mv4 = *(const float4*)(fmrow + k0);
    __syncthreads();                             // drains DMA for tile kb
    if (kb + 1 < 32) {                           // prefetch tile kb+1
      int kn = k0 + 64;
      int nb = (cur ^ 1) * 4096;
      cp16(kbase + (size_t)kn * 64, kd0 + nb);
      cp16(kbase + (size_t)kn * 64 + 512, kd8 + nb);
      cp16(vbase + kn, vd0 + nb);
      cp16(vbase + kn + 8 * S_, vd8 + nb);
    }
    const uint16_t* KsT = KsB + cur * 4096;
    const uint16_t* VsT = VsB + cur * 4096;

    // V^T A-frags for PV
    s16x4 vf[4];
    {
      int s = (2 * w + (g >> 1)) ^ (lo & 7);
      int off = s * 8 + (g & 1) * 4;
#pragma unroll
      for (int dt = 0; dt < 4; dt++)
        vf[dt] = *(const s16x4*)(VsT + (dt * 16 + lo) * 64 + off);
    }
    // K A-frags (this wave's 16 k-rows)
    bf16x8 kf[2];
#pragma unroll
    for (int kk = 0; kk < 2; kk++) {
      int s = (kk * 4 + g) ^ (lo & 7);
      kf[kk] = *(const bf16x8*)(KsT + (w * 16 + lo) * 64 + s * 8);
    }

    // S^T = K * Q^T : lane holds S[k = w*16+g*4+r][q = qt*16+lo]
    f32x4 c[2];
#pragma unroll
    for (int qt = 0; qt < 2; qt++) {
      f32x4 z = {0.f, 0.f, 0.f, 0.f};
      z = __builtin_amdgcn_mfma_f32_16x16x32_bf16(kf[0], qf[qt][0], z, 0, 0, 0);
      c[qt] = __builtin_amdgcn_mfma_f32_16x16x32_bf16(kf[1], qf[qt][1], z, 0, 0, 0);
    }

    float p[2][4];
    if (((zall >> kb) & 1u) == 0u) {   // no zero bias in this 64k chunk
#pragma unroll
      for (int qt = 0; qt < 2; qt++) {
        p[qt][0] = __builtin_amdgcn_exp2f(__builtin_fmaf(c[qt][0], LOG2E, mv4.x));
        p[qt][1] = __builtin_amdgcn_exp2f(__builtin_fmaf(c[qt][1], LOG2E, mv4.y));
        p[qt][2] = __builtin_amdgcn_exp2f(__builtin_fmaf(c[qt][2], LOG2E, mv4.z));
        p[qt][3] = __builtin_amdgcn_exp2f(__builtin_fmaf(c[qt][3], LOG2E, mv4.w));
      }
    } else {                           // rare: bias==0 -> weight 0
#pragma unroll
      for (int qt = 0; qt < 2; qt++) {
        float4 bz = *(const float4*)(bias + ((size_t)(b * S_ + q0 + qt * 16 + lo)) * S_ + k0 + w * 16 + g * 4);
        p[qt][0] = (bz.x == 0.f) ? 0.f : __builtin_amdgcn_exp2f(__builtin_fmaf(c[qt][0], LOG2E, mv4.x));
        p[qt][1] = (bz.y == 0.f) ? 0.f : __builtin_amdgcn_exp2f(__builtin_fmaf(c[qt][1], LOG2E, mv4.y));
        p[qt][2] = (bz.z == 0.f) ? 0.f : __builtin_amdgcn_exp2f(__builtin_fmaf(c[qt][2], LOG2E, mv4.z));
        p[qt][3] = (bz.w == 0.f) ? 0.f : __builtin_amdgcn_exp2f(__builtin_fmaf(c[qt][3], LOG2E, mv4.w));
      }
    }

    s16x4 pf[2];
#pragma unroll
    for (int qt = 0; qt < 2; qt++) {
      ts[qt] += (p[qt][0] + p[qt][1]) + (p[qt][2] + p[qt][3]);
      union { s16x4 v; uint32_t u[2]; } uu;
      uu.u[0] = pk2(p[qt][0], p[qt][1]);
      uu.u[1] = pk2(p[qt][2], p[qt][3]);
      pf[qt] = uu.v;
    }

    // PV: o[dt][qt] lane holds O[q=qt*16+lo][d=dt*16+g*4+r]
#pragma unroll
    for (int dt = 0; dt < 4; dt++)
#pragma unroll
      for (int qt = 0; qt < 2; qt++)
        o[dt][qt] = mfma_k16(vf[dt], pf[qt], o[dt][qt]);
  }

  // ---- epilogue: reduce 4 wave-partials, normalize, store ----
  float* OT = (float*)smem;               // [64 d][33] floats (8448 B)
  float* LS = (float*)(smem + 8448);      // [4 w][2 qt][16 lo]
#pragma unroll
  for (int qt = 0; qt < 2; qt++) {
    float v = ts[qt];
    v += __shfl_xor(v, 16);
    v += __shfl_xor(v, 32);
    ts[qt] = v;
  }
  __syncthreads();                        // main-loop LDS reads complete
  if (g == 0) {
#pragma unroll
    for (int qt = 0; qt < 2; qt++) LS[(w * 2 + qt) * 16 + lo] = ts[qt];
  }
#pragma unroll
  for (int ww = 0; ww < 4; ww++) {
    if (w == ww) {
#pragma unroll
      for (int dt = 0; dt < 4; dt++)
#pragma unroll
        for (int qt = 0; qt < 2; qt++)
#pragma unroll
          for (int r = 0; r < 4; r++) {
            int idx = (dt * 16 + g * 4 + r) * 33 + qt * 16 + lo;
            if (ww == 0) OT[idx] = o[dt][qt][r];
            else         OT[idx] += o[dt][qt][r];
          }
    }
    __syncthreads();
  }
  {
    int q = t >> 3, dseg = (t & 7) * 8;   // q in [0,32), 8 d per thread
    int qt2 = q >> 4, lo2 = q & 15;
    float lsum = LS[(0 * 2 + qt2) * 16 + lo2] + LS[(1 * 2 + qt2) * 16 + lo2] +
                 LS[(2 * 2 + qt2) * 16 + lo2] + LS[(3 * 2 + qt2) * 16 + lo2];
    float linv = 1.0f / fmaxf(lsum, 1e-30f);
    float* ob = out + ((size_t)(b * S_ + q0 + q)) * H_ + h * DK_ + dseg;
#pragma unroll
    for (int i = 0; i < 2; i++) {
      float4 v;
      v.x = OT[(dseg + i * 4 + 0) * 33 + q] * linv;
      v.y = OT[(dseg + i * 4 + 1) * 33 + q] * linv;
      v.z = OT[(dseg + i * 4 + 2) * 33 + q] * linv;
      v.w = OT[(dseg + i * 4 + 3) * 33 + q] * linv;
      *(float4*)(ob + i * 4) = v;
    }
  }
}

// ---------------------------------------------------------------------------
extern "C" void kernel_launch(void* const* d_in, const int* in_sizes, int n_in,
                              void* d_out, int out_size, void* d_ws, size_t ws_size,
                              hipStream_t stream) {
  const float* query = (const float*)d_in[0];
  const float* key   = (const float*)d_in[1];
  const float* value = (const float*)d_in[2];
  const float* bias  = (const float*)d_in[3];
  const int*   mask  = (const int*)d_in[4];
  const float* Wq = (const float*)d_in[5];
  const float* bq = (const float*)d_in[6];
  const float* Wk = (const float*)d_in[7];
  const float* bk = (const float*)d_in[8];
  const float* Wv = (const float*)d_in[9];
  const float* bv = (const float*)d_in[10];

  char* ws = (char*)d_ws;
  uint32_t* zrow = (uint32_t*)ws;                             // 16 KB
  float*    fmL  = (float*)(ws + 16384);                      // 16 KB
  uint16_t* Qb = (uint16_t*)(ws + (size_t)(1 << 20));         // 4 MB
  uint16_t* Kb = (uint16_t*)(ws + (size_t)(5 << 20));         // 4 MB
  uint16_t* Vt = (uint16_t*)(ws + (size_t)(9 << 20));         // 4 MB

  ProjArgs pa;
  pa.X[0] = query; pa.X[1] = key; pa.X[2] = value;
  pa.W[0] = Wq;    pa.W[1] = Wk;  pa.W[2] = Wv;
  pa.Bv[0] = bq;   pa.Bv[1] = bk; pa.Bv[2] = bv;
  pa.O[0] = Qb;    pa.O[1] = Kb;  pa.O[2] = Vt;
  pa.bias = bias;  pa.mask = mask;
  pa.zrow = zrow;  pa.fmL = fmL;

  prep_proj_kernel<<<1281, 256, 0, stream>>>(pa);

  attn_kernel<<<1024, 256, 0, stream>>>(Qb, Kb, Vt, zrow, fmL, bias, (float*)d_out);
}